// Round 6
// baseline (549.370 us; speedup 1.0000x reference)
//
#include <hip/hip_runtime.h>
#include <cfloat>

// ECE: N=1e6 rows, C=100 fp32 logits, int32 labels, 15 bins.
// Single fused kernel (R2's proven streaming loop, byte-identical):
//   phase 1: 4 lanes/row float4 argmax, per-row LDS atomics,
//            per-block partials -> ws[s*G + block]            (== R2 K1)
//   phase 2: __threadfence + done-counter; LAST block reduces 45xG
//            partials (fixed-order -> deterministic) and finalizes
//            (ece*100, acc*100) -> d_out[0..1].
// Plus one 4-byte hipMemsetAsync node to zero the done counter per call.

#define ECE_NBINS 15
#define ECE_NSTATS 45   // count[15], sum_acc[15], sum_conf[15]

__global__ __launch_bounds__(256) void ece_fused_kernel(
    const float* __restrict__ logits, const int* __restrict__ labels,
    float* __restrict__ ws, unsigned int* __restrict__ done,
    float* __restrict__ out, int n_rows, int G, int tiles, float n_total)
{
    __shared__ float s_stats[ECE_NSTATS];
    const int tid = threadIdx.x;
    if (tid < ECE_NSTATS) s_stats[tid] = 0.0f;
    __syncthreads();

    const int sub  = tid & 3;   // lane within 4-lane row group
    const int lrow = tid >> 2;  // 0..63 local row

    for (int tile = blockIdx.x; tile < tiles; tile += G) {
        const int r = tile * 64 + lrow;
        if (r < n_rows) {
            const float4* rowp = (const float4*)(logits + (size_t)r * 100);
            float best = -FLT_MAX;
            int   bidx = 0;
            // 25 float4 per row; lane `sub` takes indices sub, sub+4, ...
            // strict > keeps first occurrence within this lane's subset.
            #pragma unroll 7
            for (int j = sub; j < 25; j += 4) {
                const float4 v = rowp[j];
                const int e = j * 4;
                if (v.x > best) { best = v.x; bidx = e;     }
                if (v.y > best) { best = v.y; bidx = e + 1; }
                if (v.z > best) { best = v.z; bidx = e + 2; }
                if (v.w > best) { best = v.w; bidx = e + 3; }
            }
            // combine across the 4 lanes of this row; tie -> lower index
            #pragma unroll
            for (int m = 1; m <= 2; m <<= 1) {
                const float ov = __shfl_xor(best, m);
                const int   oi = __shfl_xor(bidx, m);
                if (ov > best || (ov == best && oi < bidx)) { best = ov; bidx = oi; }
            }
            if (sub == 0) {
                const float accv = (bidx == labels[r]) ? 1.0f : 0.0f;
                int bin = (int)ceilf(best * 15.0f) - 1;   // lower < c <= upper
                bin = bin < 0 ? 0 : (bin > 14 ? 14 : bin);
                atomicAdd(&s_stats[bin],      1.0f);
                atomicAdd(&s_stats[15 + bin], accv);
                atomicAdd(&s_stats[30 + bin], best);
            }
        }
    }
    __syncthreads();
    if (tid < ECE_NSTATS) ws[(size_t)tid * G + blockIdx.x] = s_stats[tid];

    // ---- last-block-done handoff ----
    __threadfence();                       // release: partials visible device-wide
    __shared__ unsigned int s_last;
    if (tid == 0) s_last = atomicAdd(done, 1u);
    __syncthreads();
    if (s_last != (unsigned int)(G - 1)) return;
    __threadfence();                       // acquire: see all blocks' partials

    // ---- phase 2: reduce 45 x G partials (fixed order -> deterministic) ----
    __shared__ float s_sum[ECE_NSTATS];
    const int wave = tid >> 6;   // 0..3
    const int lane = tid & 63;
    for (int s = wave; s < ECE_NSTATS; s += 4) {
        float v = 0.0f;
        const float* p = ws + (size_t)s * G;
        for (int j = lane; j < G; j += 64) v += p[j];
        #pragma unroll
        for (int m = 32; m >= 1; m >>= 1) v += __shfl_xor(v, m);
        if (lane == 0) s_sum[s] = v;
    }
    __syncthreads();

    if (tid < 64) {
        float ece = 0.0f, acc = 0.0f;
        if (tid < ECE_NBINS) {
            const float c = s_sum[tid];
            if (c > 0.0f) {
                const float prop = c / n_total;
                const float a = s_sum[15 + tid] / c;
                const float f = s_sum[30 + tid] / c;
                ece = fabsf(f - a) * prop;
                acc = a * prop;
            }
        }
        #pragma unroll
        for (int m = 32; m >= 1; m >>= 1) {
            ece += __shfl_xor(ece, m);
            acc += __shfl_xor(acc, m);
        }
        if (tid == 0) {
            out[0] = ece * 100.0f;
            out[1] = acc * 100.0f;
        }
    }
}

extern "C" void kernel_launch(void* const* d_in, const int* in_sizes, int n_in,
                              void* d_out, int out_size, void* d_ws, size_t ws_size,
                              hipStream_t stream) {
    const float* logits = (const float*)d_in[0];
    const int*   labels = (const int*)d_in[1];
    float*       out    = (float*)d_out;
    float*       ws     = (float*)d_ws;

    const int n_rows = in_sizes[1];              // N = 1,000,000 (labels count)
    const int tiles  = (n_rows + 63) / 64;       // 64 rows per block-tile

    int G = 2048;                                 // 8 blocks/CU on 256 CUs (R2 proven)
    const size_t maxG = (ws_size / sizeof(float) - 128) / ECE_NSTATS;
    if ((size_t)G > maxG) G = (int)maxG;
    if (G > tiles) G = tiles;
    if (G < 1) G = 1;

    // done counter on its own 256-B-aligned slot after the partials
    size_t coff = ((size_t)ECE_NSTATS * G * sizeof(float) + 255) & ~(size_t)255;
    unsigned int* done = (unsigned int*)((char*)d_ws + coff);

    hipMemsetAsync(done, 0, sizeof(unsigned int), stream);
    ece_fused_kernel<<<G, 256, 0, stream>>>(logits, labels, ws, done, out,
                                            n_rows, G, tiles, (float)n_rows);
}

// Round 7
// 79.823 us; speedup vs baseline: 6.8823x; 6.8823x over previous
//
#include <hip/hip_runtime.h>
#include <cfloat>

// ECE: N=1e6 rows, C=100 fp32 logits, int32 labels, 15 bins.
// K1: grid-stride tiles, 4 lanes/row float4 loads, argmax via shfl,
//     per-row LDS atomics; per-block partials -> ws[s*G + block].
// K2: 45 blocks, block s reduces ws[s*G..s*G+G) -> red[s]  (coalesced).
// K3: 1 wave finalizes (ece*100, acc*100) -> d_out[0..1].
// (Round-2 proven structure: 79.5 us. R3/R4/R5/R6 variants all regressed
//  or tied; notably device-scope __threadfence per block (R6) collapses
//  read BW to 350 GB/s via per-block L2 writeback+invalidate.)

#define ECE_NBINS 15
#define ECE_NSTATS 45   // count[15], sum_acc[15], sum_conf[15]

__global__ __launch_bounds__(256) void ece_partial_kernel(
    const float* __restrict__ logits, const int* __restrict__ labels,
    float* __restrict__ ws, int n_rows, int G, int tiles)
{
    __shared__ float s_stats[ECE_NSTATS];
    const int tid = threadIdx.x;
    if (tid < ECE_NSTATS) s_stats[tid] = 0.0f;
    __syncthreads();

    const int sub  = tid & 3;   // lane within 4-lane row group
    const int lrow = tid >> 2;  // 0..63 local row

    for (int tile = blockIdx.x; tile < tiles; tile += G) {
        const int r = tile * 64 + lrow;
        if (r < n_rows) {
            const float4* rowp = (const float4*)(logits + (size_t)r * 100);
            float best = -FLT_MAX;
            int   bidx = 0;
            // 25 float4 per row; lane `sub` takes indices sub, sub+4, ...
            // strict > keeps first occurrence within this lane's subset.
            #pragma unroll 7
            for (int j = sub; j < 25; j += 4) {
                const float4 v = rowp[j];
                const int e = j * 4;
                if (v.x > best) { best = v.x; bidx = e;     }
                if (v.y > best) { best = v.y; bidx = e + 1; }
                if (v.z > best) { best = v.z; bidx = e + 2; }
                if (v.w > best) { best = v.w; bidx = e + 3; }
            }
            // combine across the 4 lanes of this row; tie -> lower index
            #pragma unroll
            for (int m = 1; m <= 2; m <<= 1) {
                const float ov = __shfl_xor(best, m);
                const int   oi = __shfl_xor(bidx, m);
                if (ov > best || (ov == best && oi < bidx)) { best = ov; bidx = oi; }
            }
            if (sub == 0) {
                const float accv = (bidx == labels[r]) ? 1.0f : 0.0f;
                int bin = (int)ceilf(best * 15.0f) - 1;   // lower < c <= upper
                bin = bin < 0 ? 0 : (bin > 14 ? 14 : bin);
                atomicAdd(&s_stats[bin],      1.0f);
                atomicAdd(&s_stats[15 + bin], accv);
                atomicAdd(&s_stats[30 + bin], best);
            }
        }
    }
    __syncthreads();
    if (tid < ECE_NSTATS) ws[(size_t)tid * G + blockIdx.x] = s_stats[tid];
}

// Block s sums ws[s*G .. s*G+G) -> red[s]. Coalesced, 45 blocks in parallel.
__global__ __launch_bounds__(256) void ece_reduce_kernel(
    const float* __restrict__ ws, float* __restrict__ red, int G)
{
    const int s = blockIdx.x;
    const float* p = ws + (size_t)s * G;
    float v = 0.0f;
    for (int j = threadIdx.x; j < G; j += 256) v += p[j];

    __shared__ float sw[4];
    #pragma unroll
    for (int m = 32; m >= 1; m >>= 1) v += __shfl_xor(v, m);
    if ((threadIdx.x & 63) == 0) sw[threadIdx.x >> 6] = v;
    __syncthreads();
    if (threadIdx.x == 0) red[s] = sw[0] + sw[1] + sw[2] + sw[3];
}

__global__ __launch_bounds__(64) void ece_finalize_kernel(
    const float* __restrict__ red, float* __restrict__ out, float n_total)
{
    const int lane = threadIdx.x;
    float ece = 0.0f, acc = 0.0f;
    if (lane < ECE_NBINS) {
        const float cnt = red[lane];
        if (cnt > 0.0f) {
            const float prop = cnt / n_total;
            const float a = red[15 + lane] / cnt;
            const float c = red[30 + lane] / cnt;
            ece = fabsf(c - a) * prop;
            acc = a * prop;
        }
    }
    #pragma unroll
    for (int m = 32; m >= 1; m >>= 1) {
        ece += __shfl_xor(ece, m);
        acc += __shfl_xor(acc, m);
    }
    if (lane == 0) {
        out[0] = ece * 100.0f;
        out[1] = acc * 100.0f;
    }
}

extern "C" void kernel_launch(void* const* d_in, const int* in_sizes, int n_in,
                              void* d_out, int out_size, void* d_ws, size_t ws_size,
                              hipStream_t stream) {
    const float* logits = (const float*)d_in[0];
    const int*   labels = (const int*)d_in[1];
    float*       out    = (float*)d_out;
    float*       ws     = (float*)d_ws;

    const int n_rows = in_sizes[1];              // N = 1,000,000 (labels count)
    const int tiles  = (n_rows + 63) / 64;       // 64 rows per block-tile

    int G = 2048;                                 // 8 blocks/CU on 256 CUs
    const size_t maxG = (ws_size / sizeof(float) - ECE_NSTATS) / ECE_NSTATS;
    if ((size_t)G > maxG) G = (int)maxG;
    if (G > tiles) G = tiles;
    if (G < 1) G = 1;

    float* red = ws + (size_t)ECE_NSTATS * G;    // 45 reduced stats

    ece_partial_kernel<<<G, 256, 0, stream>>>(logits, labels, ws, n_rows, G, tiles);
    ece_reduce_kernel<<<ECE_NSTATS, 256, 0, stream>>>((const float*)ws, red, G);
    ece_finalize_kernel<<<1, 64, 0, stream>>>((const float*)red, out, (float)n_rows);
}

// Round 8
// 76.634 us; speedup vs baseline: 7.1688x; 1.0416x over previous
//
#include <hip/hip_runtime.h>
#include <cfloat>

// ECE: N=1e6 rows, C=100 fp32 logits, int32 labels, 15 bins.
// K1: grid-stride tiles; *8 lanes per row* so each 8-lane group reads
//     fully dense 128-B cache lines (3 float4 rounds + 4-B scalar tail);
//     argmax via 3-step shfl; per-row LDS atomics; partials -> ws[s*G+b].
// K2: 45 blocks, block s reduces ws[s*G..s*G+G) -> red[s]  (coalesced).
// K3: 1 wave finalizes (ece*100, acc*100) -> d_out[0..1].
// (R2 structure otherwise; R3/R4/R5/R6 all regressed or tied. R6: per-block
//  device-scope __threadfence collapses read BW 8.5x — never fence in a
//  streaming epilogue on 8-XCD CDNA4.)

#define ECE_NBINS 15
#define ECE_NSTATS 45   // count[15], sum_acc[15], sum_conf[15]

__global__ __launch_bounds__(256) void ece_partial_kernel(
    const float* __restrict__ logits, const int* __restrict__ labels,
    float* __restrict__ ws, int n_rows, int G, int tiles)
{
    __shared__ float s_stats[ECE_NSTATS];
    const int tid = threadIdx.x;
    if (tid < ECE_NSTATS) s_stats[tid] = 0.0f;
    __syncthreads();

    const int sub  = tid & 7;   // lane within 8-lane row group
    const int lrow = tid >> 3;  // 0..31 local row

    for (int tile = blockIdx.x; tile < tiles; tile += G) {
        const int r = tile * 32 + lrow;
        if (r < n_rows) {
            const float*  rowf = logits + (size_t)r * 100;
            const float4* rowp = (const float4*)rowf;
            float best = -FLT_MAX;
            int   bidx = 0;
            // 8-lane group covers float4 j = sub+8k, k=0..2: bytes 0..383
            // as dense 128-B lines; strict > keeps first occurrence.
            #pragma unroll
            for (int k = 0; k < 3; ++k) {
                const float4 v = rowp[sub + 8 * k];
                const int e = (sub + 8 * k) * 4;
                if (v.x > best) { best = v.x; bidx = e;     }
                if (v.y > best) { best = v.y; bidx = e + 1; }
                if (v.z > best) { best = v.z; bidx = e + 2; }
                if (v.w > best) { best = v.w; bidx = e + 3; }
            }
            if (sub < 4) {                     // scalar tail elems 96..99
                const float vl = rowf[96 + sub];
                if (vl > best) { best = vl; bidx = 96 + sub; }
            }
            // combine across the 8 lanes of this row; tie -> lower index
            #pragma unroll
            for (int m = 1; m <= 4; m <<= 1) {
                const float ov = __shfl_xor(best, m);
                const int   oi = __shfl_xor(bidx, m);
                if (ov > best || (ov == best && oi < bidx)) { best = ov; bidx = oi; }
            }
            if (sub == 0) {
                const float accv = (bidx == labels[r]) ? 1.0f : 0.0f;
                int bin = (int)ceilf(best * 15.0f) - 1;   // lower < c <= upper
                bin = bin < 0 ? 0 : (bin > 14 ? 14 : bin);
                atomicAdd(&s_stats[bin],      1.0f);
                atomicAdd(&s_stats[15 + bin], accv);
                atomicAdd(&s_stats[30 + bin], best);
            }
        }
    }
    __syncthreads();
    if (tid < ECE_NSTATS) ws[(size_t)tid * G + blockIdx.x] = s_stats[tid];
}

// Block s sums ws[s*G .. s*G+G) -> red[s]. Coalesced, 45 blocks in parallel.
__global__ __launch_bounds__(256) void ece_reduce_kernel(
    const float* __restrict__ ws, float* __restrict__ red, int G)
{
    const int s = blockIdx.x;
    const float* p = ws + (size_t)s * G;
    float v = 0.0f;
    for (int j = threadIdx.x; j < G; j += 256) v += p[j];

    __shared__ float sw[4];
    #pragma unroll
    for (int m = 32; m >= 1; m >>= 1) v += __shfl_xor(v, m);
    if ((threadIdx.x & 63) == 0) sw[threadIdx.x >> 6] = v;
    __syncthreads();
    if (threadIdx.x == 0) red[s] = sw[0] + sw[1] + sw[2] + sw[3];
}

__global__ __launch_bounds__(64) void ece_finalize_kernel(
    const float* __restrict__ red, float* __restrict__ out, float n_total)
{
    const int lane = threadIdx.x;
    float ece = 0.0f, acc = 0.0f;
    if (lane < ECE_NBINS) {
        const float cnt = red[lane];
        if (cnt > 0.0f) {
            const float prop = cnt / n_total;
            const float a = red[15 + lane] / cnt;
            const float c = red[30 + lane] / cnt;
            ece = fabsf(c - a) * prop;
            acc = a * prop;
        }
    }
    #pragma unroll
    for (int m = 32; m >= 1; m >>= 1) {
        ece += __shfl_xor(ece, m);
        acc += __shfl_xor(acc, m);
    }
    if (lane == 0) {
        out[0] = ece * 100.0f;
        out[1] = acc * 100.0f;
    }
}

extern "C" void kernel_launch(void* const* d_in, const int* in_sizes, int n_in,
                              void* d_out, int out_size, void* d_ws, size_t ws_size,
                              hipStream_t stream) {
    const float* logits = (const float*)d_in[0];
    const int*   labels = (const int*)d_in[1];
    float*       out    = (float*)d_out;
    float*       ws     = (float*)d_ws;

    const int n_rows = in_sizes[1];              // N = 1,000,000 (labels count)
    const int tiles  = (n_rows + 31) / 32;       // 32 rows per block-tile

    int G = 2048;                                 // 8 blocks/CU on 256 CUs
    const size_t maxG = (ws_size / sizeof(float) - ECE_NSTATS) / ECE_NSTATS;
    if ((size_t)G > maxG) G = (int)maxG;
    if (G > tiles) G = tiles;
    if (G < 1) G = 1;

    float* red = ws + (size_t)ECE_NSTATS * G;    // 45 reduced stats

    ece_partial_kernel<<<G, 256, 0, stream>>>(logits, labels, ws, n_rows, G, tiles);
    ece_reduce_kernel<<<ECE_NSTATS, 256, 0, stream>>>((const float*)ws, red, G);
    ece_finalize_kernel<<<1, 64, 0, stream>>>((const float*)red, out, (float)n_rows);
}